// Round 13
// baseline (181.243 us; speedup 1.0000x reference)
//
#include <hip/hip_runtime.h>
#include <hip/hip_bf16.h>
#include <stdint.h>

// x[4,2048,4096] f32, qweight[4096,4096] i32, scale/zp f32 scalars, bias[4096] f32
// out = x @ (scale*(q-zp))^T + bias : M=8192, N=4096, K=4096, f32 out.
// i8 path: W = s(q-128) + s(128-zp); x ~= rowscale * qx (i8).
// out = (rowscale*s) * (qx @ (q-128)^T)_i32  +  s(128-zp)*rowsum(x)  + bias.
#define M_DIM 8192
#define N_DIM 4096
#define K_DIM 4096

typedef __attribute__((ext_vector_type(4))) int i32x4;
typedef __attribute__((ext_vector_type(8))) __bf16 bf16x8;
typedef __attribute__((ext_vector_type(4))) float f32x4;
typedef __attribute__((ext_vector_type(8))) unsigned short ushort8;

__device__ __forceinline__ unsigned short f2bf(float f) {
  union { float f; uint32_t u; } v; v.f = f;
  uint32_t u = v.u;
  return (unsigned short)((u + 0x7FFFu + ((u >> 16) & 1u)) >> 16);  // RNE
}

__device__ __forceinline__ void gload_lds16(const void* g, void* l) {
  __builtin_amdgcn_global_load_lds((const __attribute__((address_space(1))) void*)g,
                                   (__attribute__((address_space(3))) void*)l,
                                   16, 0, 0);
}

#define RAW_BAR() asm volatile("s_barrier" ::: "memory")
#define VMW(n) asm volatile("s_waitcnt vmcnt(" #n ")" ::: "memory")
#define LGKM0()                                        \
  do {                                                 \
    asm volatile("s_waitcnt lgkmcnt(0)" ::: "memory"); \
    __builtin_amdgcn_sched_barrier(0);                 \
  } while (0)
#define SBAR0() __builtin_amdgcn_sched_barrier(0)

// ---- merged prepack: blocks 0..M-1 quantize one x row each;
//      blocks >= M grid-stride convert qweight -> i8 (q-128, exact).
#define WN4 ((long long)N_DIM * K_DIM / 4)
#define WBLOCKS 2048

__global__ __launch_bounds__(256) void prepack_kernel(
    const float* __restrict__ x, const int* __restrict__ q,
    const float* __restrict__ scale, const float* __restrict__ zp,
    char* __restrict__ xq, char* __restrict__ wq,
    float* __restrict__ rsw, float* __restrict__ corr) {
  const int b = blockIdx.x;
  const int t = threadIdx.x;
  if (b < M_DIM) {
    // ---- x row quant ----
    const int row = b;
    const float4* xr = (const float4*)(x + (size_t)row * K_DIM);
    float4 v[4];
    float mx = 0.f;
    #pragma unroll
    for (int i = 0; i < 4; ++i) {
      v[i] = xr[i * 256 + t];
      mx = fmaxf(mx, fmaxf(fmaxf(fabsf(v[i].x), fabsf(v[i].y)),
                           fmaxf(fabsf(v[i].z), fabsf(v[i].w))));
    }
    __shared__ float redm[4], reds[4];
    #pragma unroll
    for (int off = 32; off; off >>= 1) mx = fmaxf(mx, __shfl_xor(mx, off));
    if ((t & 63) == 0) redm[t >> 6] = mx;
    __syncthreads();
    mx = fmaxf(fmaxf(redm[0], redm[1]), fmaxf(redm[2], redm[3]));
    mx = fmaxf(mx, 1e-20f);
    const float inv = 127.f / mx;
    float sum = 0.f;
    int* xqo = (int*)xq + (size_t)row * (K_DIM / 4);
    #pragma unroll
    for (int i = 0; i < 4; ++i) {
      sum += v[i].x + v[i].y + v[i].z + v[i].w;
      int q0 = (int)rintf(v[i].x * inv), q1 = (int)rintf(v[i].y * inv);
      int q2 = (int)rintf(v[i].z * inv), q3 = (int)rintf(v[i].w * inv);
      xqo[i * 256 + t] = (q0 & 255) | ((q1 & 255) << 8) | ((q2 & 255) << 16) | (q3 << 24);
    }
    #pragma unroll
    for (int off = 32; off; off >>= 1) sum += __shfl_xor(sum, off);
    if ((t & 63) == 0) reds[t >> 6] = sum;
    __syncthreads();
    if (t == 0) {
      const float sw = scale[0], zw = zp[0];
      rsw[row] = (mx / 127.f) * sw;
      corr[row] = sw * (128.f - zw) * (reds[0] + reds[1] + reds[2] + reds[3]);
    }
  } else {
    // ---- w convert ----
    long long i = (long long)(b - M_DIM) * 256 + t;
    const long long stride = (long long)WBLOCKS * 256;
    int* wo = (int*)wq;
    for (; i < WN4; i += stride) {
      const int4 a = ((const int4*)q)[i];
      wo[i] = ((a.x - 128) & 255) | (((a.y - 128) & 255) << 8) |
              (((a.z - 128) & 255) << 16) | ((a.w - 128) << 24);
    }
  }
}

// ---- main GEMM: i8, 256x256 tile, BK=64, 8 waves (2Mx4N, 128x64/wave),
// mfma_i32_16x16x64_i8. Round-13: 4 fine phases per K-tile (round-7-proven
// shadowed-read interleave) x depth-3 DMA prefetch (round-11; 4 bufs, tile X
// -> buf X&3, stage tile X+3, one gload per phase).
// Per phase: {LGKM0 [waits reads issued last phase]; 8-MFMA quadrant
// (setprio); stage 1 gload; [VMW(7)@PH3: retires exactly tile X+1]; issue
// next quadrant's reads; barrier}.
// Reads/K-tile: Q1=af0-3+bfv0-1 (6), Q2=bfv2-3 (2), Q3=af4-7 (4).
// Single af[8]+bfv[4] set: every overwrite >=1 phase after last consumer.
// Swizzle (zero-conflict proven): 64B rows, 16B granules, g' = g^((row>>1)&3).
#define NTILE (K_DIM / 64)        // 64 K-tiles
#define BUFB 32768                // per buf: A 16 KB + B 16 KB

__global__ __launch_bounds__(512, 2) void gemm256_i8_kernel(
    const char* __restrict__ xq, const char* __restrict__ wq,
    const float* __restrict__ rsw, const float* __restrict__ corr,
    const float* __restrict__ bias, float* __restrict__ out) {
  __shared__ char lds[4 * BUFB];  // 128 KiB

  const int t = threadIdx.x;
  const int lane = t & 63;
  const int wid = t >> 6;          // 0..7
  const int wr = wid >> 2;         // 0..1  (M half)
  const int wc = wid & 3;          // 0..3  (N quarter)
  const int fr = lane & 15, fq = lane >> 4;

  // XCD-aware bijective swizzle; grid = 512 (divisible by 8)
  const int bid = blockIdx.x;
  const int swz = ((bid & 7) << 6) | (bid >> 3);
  const int bx = swz & 15;         // N/256 = 16
  const int by = swz >> 4;         // M/256 = 32
  const int brow = by * 256, bcol = bx * 256;

  // staging: half-tile = 128 rows x 64 B = 8 KB = 512 thr x 1 gload16.
  const int gsrc = (t & 3) ^ ((t >> 3) & 3);
  const char* gAs = xq + (size_t)(brow + (t >> 2)) * K_DIM + gsrc * 16;
  const char* gBs = wq + (size_t)(bcol + (t >> 2)) * K_DIM + gsrc * 16;

  // read-side: lane (fr,fq) wants global granule fq of its row -> LDS granule
  // fq ^ ((fr>>1)&3).
  const int gsel16 = (fq ^ ((fr >> 1) & 3)) * 16;
  const int arow = (wr * 128 + fr) * 64;           // + m*1024, byte offsets
  const int brow_o = 16384 + (wc * 64 + fr) * 64;  // + n*1024

  i32x4 af[8], bfv[4];
  i32x4 acc[8][4] = {};

  #define LD_A(b, m) (*(const i32x4*)(lds + (b) * BUFB + arow + (m) * 1024 + gsel16))
  #define LD_B(b, n) (*(const i32x4*)(lds + (b) * BUFB + brow_o + (n) * 1024 + gsel16))

  #define RD_Q1(b)                                                             \
    { af[0] = LD_A(b, 0); af[1] = LD_A(b, 1); af[2] = LD_A(b, 2);              \
      af[3] = LD_A(b, 3); bfv[0] = LD_B(b, 0); bfv[1] = LD_B(b, 1); }
  #define RD_Q2(b) { bfv[2] = LD_B(b, 2); bfv[3] = LD_B(b, 3); }
  #define RD_Q3(b)                                                             \
    { af[4] = LD_A(b, 4); af[5] = LD_A(b, 5); af[6] = LD_A(b, 6);              \
      af[7] = LD_A(b, 7); }

  #define STG(isB, h, tile, b)                                                 \
    do {                                                                       \
      char* l_ = lds + (b) * BUFB + (isB) * 16384 + (h) * 8192 + t * 16;       \
      const char* g_ = ((isB) ? gBs : gAs) + (size_t)(h) * 128 * K_DIM +       \
                       (size_t)(tile) * 64;                                    \
      gload_lds16(g_, l_);                                                     \
    } while (0)

  // Quadrant (MS in {0,4}, NS in {0,2}): 8 x mfma_i32_16x16x64.
  #define MMQ(MS, NS)                                                          \
    __builtin_amdgcn_s_setprio(1);                                             \
    _Pragma("unroll")                                                          \
    for (int m = 0; m < 4; ++m) {                                              \
      _Pragma("unroll")                                                        \
      for (int n = 0; n < 2; ++n)                                              \
        acc[MS + m][NS + n] = __builtin_amdgcn_mfma_i32_16x16x64_i8(           \
            af[MS + m], bfv[NS + n], acc[MS + m][NS + n], 0, 0, 0);            \
    }                                                                          \
    __builtin_amdgcn_s_setprio(0);                                             \
    SBAR0();

  // prologue: stage tiles 0,1,2 (bufs 0,1,2; 12 gloads, order B0,B1,A0,A1 per
  // tile); VMW(8) retires tile 0 (leaves 1,2 = 8 in flight); barrier; RD_Q1(0).
  STG(1, 0, 0, 0); STG(1, 1, 0, 0); STG(0, 0, 0, 0); STG(0, 1, 0, 0);
  STG(1, 0, 1, 1); STG(1, 1, 1, 1); STG(0, 0, 1, 1); STG(0, 1, 1, 1);
  STG(1, 0, 2, 2); STG(1, 1, 2, 2); STG(0, 0, 2, 2); STG(0, 1, 2, 2);
  VMW(8);
  RAW_BAR();
  RD_Q1(0)

  // steady X = 0..60 (stages tile X+3).
  // vm ledger entering PH1(X): {X+1:4, X+2:4} = 8. PH1 +1, PH2 +1, PH3 +1
  // -> 11; VMW(7) retires exactly tile X+1's 4 (publishes X+1); PH4 +1 -> 8.
  // RD_Q1(X+1)@PH4 follows VMW(7)+barrier (cross-wave visible). LDS write
  // hazards: STG into buf (X-1)&3 whose last reads (Q3(X-1)) lgkm-drained at
  // PH3(X-1) entry, >=2 barriers before PH1(X)'s stage.
  // Reg liveness: Q2(X+1) overwrite of bfv2-3 happens PH1(X+1), after their
  // last use @PH4(X); Q3(X+1)@PH2(X+1) after af4-7 use @PH4(X); Q1(X+1)@PH4(X)
  // after af0-3 use @PH2(X) and bfv0-1 use @PH3(X).
  for (int X = 0; X <= 60; ++X) {
    const int b  = X & 3;
    const int bN = (X + 1) & 3;
    const int B3 = (X + 3) & 3;
    const int T3 = X + 3;
    // PH1: Q1(X) ready
    LGKM0(); MMQ(0, 0) STG(1, 0, T3, B3); RD_Q2(b) RAW_BAR();
    // PH2: Q2(X) ready
    LGKM0(); MMQ(0, 2) STG(1, 1, T3, B3); RD_Q3(b) RAW_BAR();
    // PH3: Q3(X) ready; publish tile X+1
    LGKM0(); MMQ(4, 0) STG(0, 0, T3, B3); VMW(7); RAW_BAR();
    // PH4: no wait (af4-7 ready @PH3, bfv2-3 @PH2); read Q1(X+1)
    MMQ(4, 2) STG(0, 1, T3, B3); RD_Q1(bN) RAW_BAR();
  }
  // X=61 (buf1): no stage; in-flight {62:4, 63:4}; VMW(4) publishes 62.
  LGKM0(); MMQ(0, 0) RD_Q2(1) RAW_BAR();
  LGKM0(); MMQ(0, 2) RD_Q3(1) RAW_BAR();
  LGKM0(); MMQ(4, 0) VMW(4); RAW_BAR();
  MMQ(4, 2) RD_Q1(2) RAW_BAR();
  // X=62 (buf2): in-flight {63:4}; VMW(0) publishes 63.
  LGKM0(); MMQ(0, 0) RD_Q2(2) RAW_BAR();
  LGKM0(); MMQ(0, 2) RD_Q3(2) RAW_BAR();
  LGKM0(); MMQ(4, 0) VMW(0); RAW_BAR();
  MMQ(4, 2) RD_Q1(3) RAW_BAR();
  // X=63 (buf3): final tile.
  LGKM0(); MMQ(0, 0) RD_Q2(3) RAW_BAR();
  LGKM0(); MMQ(0, 2) RD_Q3(3) RAW_BAR();
  LGKM0(); MMQ(4, 0) RAW_BAR();
  MMQ(4, 2)

  #undef LD_A
  #undef LD_B
  #undef RD_Q1
  #undef RD_Q2
  #undef RD_Q3
  #undef STG
  #undef MMQ

  // epilogue: C/D layout col = lane&15, row = (lane>>4)*4 + j.
  // out = acc*rsw[row] + corr[row] + bias[col].
  float bv[4];
  #pragma unroll
  for (int n = 0; n < 4; ++n) bv[n] = bias[bcol + wc * 64 + n * 16 + fr];
  #pragma unroll
  for (int m = 0; m < 8; ++m) {
    #pragma unroll
    for (int j = 0; j < 4; ++j) {
      const int row = brow + wr * 128 + m * 16 + fq * 4 + j;
      const float rs_ = rsw[row], co_ = corr[row];
      #pragma unroll
      for (int n = 0; n < 4; ++n) {
        const int col = bcol + wc * 64 + n * 16 + fr;
        out[(size_t)row * N_DIM + col] = (float)acc[m][n][j] * rs_ + co_ + bv[n];
      }
    }
  }
}

// ---- fallback (ws too small): fused dequant bf16 128^2 tile, correct but slower ----
__global__ __launch_bounds__(256) void gemm_fallback_kernel(
    const float* __restrict__ x, const int* __restrict__ qw,
    const float* __restrict__ scale, const float* __restrict__ zp,
    const float* __restrict__ bias, float* __restrict__ out) {
  __shared__ unsigned short lds_a[128 * 32];
  __shared__ unsigned short lds_b[128 * 32];
  const int t = threadIdx.x;
  const int lane = t & 63;
  const int wid = t >> 6;
  const int wr = wid >> 1, wc = wid & 1;
  const int fr = lane & 15, fq = lane >> 4;
  const int nwg = gridDim.x;
  const int cpx = nwg >> 3;
  const int bid = blockIdx.x;
  const int swz = (bid & 7) * cpx + (bid >> 3);
  const int bx = swz & 31, by = swz >> 5;
  const int brow = by * 128, bcol = bx * 128;
  const int r0 = t >> 2, c8 = (t & 3) * 8;
  f32x4 acc[4][4] = {};
  const float ss = scale[0], zs = zp[0];
  for (int kk = 0; kk < K_DIM; kk += 32) {
    ushort8 ua[2], ub[2];
    #pragma unroll
    for (int i = 0; i < 2; ++i) {
      const float* gp = x + (size_t)(brow + i * 64 + r0) * K_DIM + kk + c8;
      float4 v0 = *(const float4*)gp;
      float4 v1 = *(const float4*)(gp + 4);
      ua[i][0] = f2bf(v0.x); ua[i][1] = f2bf(v0.y); ua[i][2] = f2bf(v0.z); ua[i][3] = f2bf(v0.w);
      ua[i][4] = f2bf(v1.x); ua[i][5] = f2bf(v1.y); ua[i][6] = f2bf(v1.z); ua[i][7] = f2bf(v1.w);
      const int* qp = qw + (size_t)(bcol + i * 64 + r0) * K_DIM + kk + c8;
      int4 q0 = *(const int4*)qp;
      int4 q1 = *(const int4*)(qp + 4);
      ub[i][0] = f2bf(ss * ((float)q0.x - zs)); ub[i][1] = f2bf(ss * ((float)q0.y - zs));
      ub[i][2] = f2bf(ss * ((float)q0.z - zs)); ub[i][3] = f2bf(ss * ((float)q0.w - zs));
      ub[i][4] = f2bf(ss * ((float)q1.x - zs)); ub[i][5] = f2bf(ss * ((float)q1.y - zs));
      ub[i][6] = f2bf(ss * ((float)q1.z - zs)); ub[i][7] = f2bf(ss * ((float)q1.w - zs));
    }
    __syncthreads();
    #pragma unroll
    for (int i = 0; i < 2; ++i) {
      *(ushort8*)(lds_a + ((size_t)i * 256 + t) * 8) = ua[i];
      *(ushort8*)(lds_b + ((size_t)i * 256 + t) * 8) = ub[i];
    }
    __syncthreads();
    bf16x8 af[4], bfr[4];
    #pragma unroll
    for (int m = 0; m < 4; ++m)
      af[m] = *(const bf16x8*)(lds_a + (wr * 64 + m * 16 + fr) * 32 + fq * 8);
    #pragma unroll
    for (int n = 0; n < 4; ++n)
      bfr[n] = *(const bf16x8*)(lds_b + (wc * 64 + n * 16 + fr) * 32 + fq * 8);
    #pragma unroll
    for (int m = 0; m < 4; ++m)
      #pragma unroll
      for (int n = 0; n < 4; ++n)
        acc[m][n] = __builtin_amdgcn_mfma_f32_16x16x32_bf16(af[m], bfr[n], acc[m][n], 0, 0, 0);
  }
  #pragma unroll
  for (int n = 0; n < 4; ++n) {
    const int col = bcol + wc * 64 + n * 16 + fr;
    const float bvv = bias[col];
    #pragma unroll
    for (int m = 0; m < 4; ++m) {
      const int rowb = brow + wr * 64 + m * 16 + fq * 4;
      #pragma unroll
      for (int j = 0; j < 4; ++j)
        out[(size_t)(rowb + j) * N_DIM + col] = acc[m][n][j] + bvv;
    }
  }
}

extern "C" void kernel_launch(void* const* d_in, const int* in_sizes, int n_in,
                              void* d_out, int out_size, void* d_ws, size_t ws_size,
                              hipStream_t stream) {
  const float* x = (const float*)d_in[0];
  const int* qw = (const int*)d_in[1];
  const float* scale = (const float*)d_in[2];
  const float* zp = (const float*)d_in[3];
  const float* bias = (const float*)d_in[4];
  float* out = (float*)d_out;

  const size_t xq_bytes = (size_t)M_DIM * K_DIM;          // 32 MB
  const size_t wq_bytes = (size_t)N_DIM * K_DIM;          // 16 MB
  const size_t rsw_bytes = (size_t)M_DIM * 4;             // 32 KB
  const size_t need = xq_bytes + wq_bytes + 2 * rsw_bytes;

  if (ws_size >= need) {
    char* xq = (char*)d_ws;
    char* wq = (char*)d_ws + xq_bytes;
    float* rsw = (float*)((char*)d_ws + xq_bytes + wq_bytes);
    float* corr = rsw + M_DIM;
    prepack_kernel<<<M_DIM + WBLOCKS, 256, 0, stream>>>(x, qw, scale, zp, xq, wq, rsw, corr);
    const int grid = (M_DIM / 256) * (N_DIM / 256);  // 512, divisible by 8
    gemm256_i8_kernel<<<grid, 512, 0, stream>>>(xq, wq, rsw, corr, bias, out);
  } else {
    const int grid = (M_DIM / 128) * (N_DIM / 128);  // 2048
    gemm_fallback_kernel<<<grid, 256, 0, stream>>>(x, qw, scale, zp, bias, out);
  }
}

// Round 14
// 178.345 us; speedup vs baseline: 1.0162x; 1.0162x over previous
//
#include <hip/hip_runtime.h>
#include <hip/hip_bf16.h>
#include <stdint.h>

// x[4,2048,4096] f32, qweight[4096,4096] i32, scale/zp f32 scalars, bias[4096] f32
// out = x @ (scale*(q-zp))^T + bias : M=8192, N=4096, K=4096, f32 out.
// i8 path: W = s(q-128) + s(128-zp); x ~= rowscale * qx (i8).
// out = (rowscale*s) * (qx @ (q-128)^T)_i32  +  s(128-zp)*rowsum(x)  + bias.
#define M_DIM 8192
#define N_DIM 4096
#define K_DIM 4096

typedef __attribute__((ext_vector_type(4))) int i32x4;
typedef __attribute__((ext_vector_type(8))) __bf16 bf16x8;
typedef __attribute__((ext_vector_type(4))) float f32x4;
typedef __attribute__((ext_vector_type(8))) unsigned short ushort8;

__device__ __forceinline__ unsigned short f2bf(float f) {
  union { float f; uint32_t u; } v; v.f = f;
  uint32_t u = v.u;
  return (unsigned short)((u + 0x7FFFu + ((u >> 16) & 1u)) >> 16);  // RNE
}

__device__ __forceinline__ void gload_lds16(const void* g, void* l) {
  __builtin_amdgcn_global_load_lds((const __attribute__((address_space(1))) void*)g,
                                   (__attribute__((address_space(3))) void*)l,
                                   16, 0, 0);
}

#define RAW_BAR() asm volatile("s_barrier" ::: "memory")
#define VMW(n) asm volatile("s_waitcnt vmcnt(" #n ")" ::: "memory")
#define LGKM0()                                        \
  do {                                                 \
    asm volatile("s_waitcnt lgkmcnt(0)" ::: "memory"); \
    __builtin_amdgcn_sched_barrier(0);                 \
  } while (0)
#define SBAR0() __builtin_amdgcn_sched_barrier(0)

// ---- merged prepack: blocks 0..M-1 quantize one x row each;
//      blocks >= M grid-stride convert qweight -> i8 (q-128, exact).
#define WN4 ((long long)N_DIM * K_DIM / 4)
#define WBLOCKS 2048

__global__ __launch_bounds__(256) void prepack_kernel(
    const float* __restrict__ x, const int* __restrict__ q,
    const float* __restrict__ scale, const float* __restrict__ zp,
    char* __restrict__ xq, char* __restrict__ wq,
    float* __restrict__ rsw, float* __restrict__ corr) {
  const int b = blockIdx.x;
  const int t = threadIdx.x;
  if (b < M_DIM) {
    // ---- x row quant ----
    const int row = b;
    const float4* xr = (const float4*)(x + (size_t)row * K_DIM);
    float4 v[4];
    float mx = 0.f;
    #pragma unroll
    for (int i = 0; i < 4; ++i) {
      v[i] = xr[i * 256 + t];
      mx = fmaxf(mx, fmaxf(fmaxf(fabsf(v[i].x), fabsf(v[i].y)),
                           fmaxf(fabsf(v[i].z), fabsf(v[i].w))));
    }
    __shared__ float redm[4], reds[4];
    #pragma unroll
    for (int off = 32; off; off >>= 1) mx = fmaxf(mx, __shfl_xor(mx, off));
    if ((t & 63) == 0) redm[t >> 6] = mx;
    __syncthreads();
    mx = fmaxf(fmaxf(redm[0], redm[1]), fmaxf(redm[2], redm[3]));
    mx = fmaxf(mx, 1e-20f);
    const float inv = 127.f / mx;
    float sum = 0.f;
    int* xqo = (int*)xq + (size_t)row * (K_DIM / 4);
    #pragma unroll
    for (int i = 0; i < 4; ++i) {
      sum += v[i].x + v[i].y + v[i].z + v[i].w;
      int q0 = (int)rintf(v[i].x * inv), q1 = (int)rintf(v[i].y * inv);
      int q2 = (int)rintf(v[i].z * inv), q3 = (int)rintf(v[i].w * inv);
      xqo[i * 256 + t] = (q0 & 255) | ((q1 & 255) << 8) | ((q2 & 255) << 16) | (q3 << 24);
    }
    #pragma unroll
    for (int off = 32; off; off >>= 1) sum += __shfl_xor(sum, off);
    if ((t & 63) == 0) reds[t >> 6] = sum;
    __syncthreads();
    if (t == 0) {
      const float sw = scale[0], zw = zp[0];
      rsw[row] = (mx / 127.f) * sw;
      corr[row] = sw * (128.f - zw) * (reds[0] + reds[1] + reds[2] + reds[3]);
    }
  } else {
    // ---- w convert ----
    long long i = (long long)(b - M_DIM) * 256 + t;
    const long long stride = (long long)WBLOCKS * 256;
    int* wo = (int*)wq;
    for (; i < WN4; i += stride) {
      const int4 a = ((const int4*)q)[i];
      wo[i] = ((a.x - 128) & 255) | (((a.y - 128) & 255) << 8) |
              (((a.z - 128) & 255) << 16) | ((a.w - 128) << 24);
    }
  }
}

// ---- main GEMM (round-11/12 best): i8, 256x256 tile, BK=64, 8 waves
// (2Mx4N, 128x64/wave), mfma_i32_16x16x64_i8. 4 LDS buffers (tile X -> buf
// X&3), stage tile X+3 (depth-3 DMA prefetch), 2 phases/K-tile.
//  PH_A(X): lgkm0 [H1(X) done]; read H2(X); MFMA m0-3; stage B(X+3);
//           VMW(6) [retires B(X+1),A(X+1) -> publishes X+1]; barrier.
//  PH_B(X): lgkm0 [H2(X) done]; read H1(X+1) [af0-3 dead, bfv ping-pong];
//           MFMA m4-7; stage A(X+3); barrier.
// Swizzle (zero-conflict proven): 64B rows, 16B granules, g' = g^((row>>1)&3).
#define NTILE (K_DIM / 64)        // 64 K-tiles
#define BUFB 32768                // per buf: A 16 KB + B 16 KB

__global__ __launch_bounds__(512, 2) void gemm256_i8_kernel(
    const char* __restrict__ xq, const char* __restrict__ wq,
    const float* __restrict__ rsw, const float* __restrict__ corr,
    const float* __restrict__ bias, float* __restrict__ out) {
  __shared__ char lds[4 * BUFB];  // 128 KiB

  const int t = threadIdx.x;
  const int lane = t & 63;
  const int wid = t >> 6;          // 0..7
  const int wr = wid >> 2;         // 0..1  (M half)
  const int wc = wid & 3;          // 0..3  (N quarter)
  const int fr = lane & 15, fq = lane >> 4;

  // XCD-aware bijective swizzle; grid = 512 (divisible by 8)
  const int bid = blockIdx.x;
  const int swz = ((bid & 7) << 6) | (bid >> 3);
  const int bx = swz & 15;         // N/256 = 16
  const int by = swz >> 4;         // M/256 = 32
  const int brow = by * 256, bcol = bx * 256;

  // staging: half-tile = 128 rows x 64 B = 8 KB = 512 thr x 1 gload16.
  const int gsrc = (t & 3) ^ ((t >> 3) & 3);
  const char* gAs = xq + (size_t)(brow + (t >> 2)) * K_DIM + gsrc * 16;
  const char* gBs = wq + (size_t)(bcol + (t >> 2)) * K_DIM + gsrc * 16;

  // read-side: lane (fr,fq) wants global granule fq of its row -> LDS granule
  // fq ^ ((fr>>1)&3).
  const int gsel16 = (fq ^ ((fr >> 1) & 3)) * 16;
  const int arow = (wr * 128 + fr) * 64;           // + m*1024, byte offsets
  const int brow_o = 16384 + (wc * 64 + fr) * 64;  // + n*1024

  i32x4 af[8], bfv[2][4];
  i32x4 acc[8][4] = {};

  #define LD_A(b, m) (*(const i32x4*)(lds + (b) * BUFB + arow + (m) * 1024 + gsel16))
  #define LD_B(b, n) (*(const i32x4*)(lds + (b) * BUFB + brow_o + (n) * 1024 + gsel16))

  #define RD_H1(b, p)                                                          \
    { af[0] = LD_A(b, 0); af[1] = LD_A(b, 1); af[2] = LD_A(b, 2);              \
      af[3] = LD_A(b, 3);                                                      \
      bfv[p][0] = LD_B(b, 0); bfv[p][1] = LD_B(b, 1);                          \
      bfv[p][2] = LD_B(b, 2); bfv[p][3] = LD_B(b, 3); }
  #define RD_H2(b)                                                             \
    { af[4] = LD_A(b, 4); af[5] = LD_A(b, 5); af[6] = LD_A(b, 6);              \
      af[7] = LD_A(b, 7); }

  #define STG(isB, h, tile, b)                                                 \
    do {                                                                       \
      char* l_ = lds + (b) * BUFB + (isB) * 16384 + (h) * 8192 + t * 16;       \
      const char* g_ = ((isB) ? gBs : gAs) + (size_t)(h) * 128 * K_DIM +       \
                       (size_t)(tile) * 64;                                    \
      gload_lds16(g_, l_);                                                     \
    } while (0)

  #define MMQ(MS, p)                                                           \
    __builtin_amdgcn_s_setprio(1);                                             \
    _Pragma("unroll")                                                          \
    for (int m = 0; m < 4; ++m) {                                              \
      _Pragma("unroll")                                                        \
      for (int n = 0; n < 4; ++n)                                              \
        acc[MS + m][n] = __builtin_amdgcn_mfma_i32_16x16x64_i8(                \
            af[MS + m], bfv[p][n], acc[MS + m][n], 0, 0, 0);                   \
    }                                                                          \
    __builtin_amdgcn_s_setprio(0);                                             \
    SBAR0();

  // PH_A(X): b=X&3, p=X&1, B3=(X+3)&3, Xp3=X+3, WT = VMW level.
  #define PH_A(b, p, Xp3, B3, WT_)                                             \
    LGKM0(); RD_H2(b) MMQ(0, p)                                                \
    STG(1, 0, Xp3, B3); STG(1, 1, Xp3, B3); WT_; RAW_BAR();
  // PH_B(X): bN=(X+1)&3, np=p^1.
  #define PH_B(bN, p, np, Xp3, B3)                                             \
    LGKM0(); RD_H1(bN, np) MMQ(4, p)                                           \
    STG(0, 0, Xp3, B3); STG(0, 1, Xp3, B3); RAW_BAR();

  #define TILE_FULL(b, bN, B3, p, np, Xp3)                                     \
    PH_A(b, p, Xp3, B3, VMW(6))                                                \
    PH_B(bN, p, np, Xp3, B3)

  // prologue: stage tiles 0,1,2 (bufs 0,1,2; 12 gloads); VMW(8) retires tile 0
  // (leaves tiles 1,2 = 8 in flight); barrier; pre-read H1(0).
  STG(1, 0, 0, 0); STG(1, 1, 0, 0); STG(0, 0, 0, 0); STG(0, 1, 0, 0);
  STG(1, 0, 1, 1); STG(1, 1, 1, 1); STG(0, 0, 1, 1); STG(0, 1, 1, 1);
  STG(1, 0, 2, 2); STG(1, 1, 2, 2); STG(0, 0, 2, 2); STG(0, 1, 2, 2);
  VMW(8);
  RAW_BAR();
  RD_H1(0, 0)

  // steady X=0..59: bufs cycle 0,1,2,3; parity 0,1,0,1.
  // vm ledger: before PH_A(X): tiles X+1,X+2 in flight (8); +B(X+3) -> 10;
  // VMW(6) retires B(X+1)+A(X+1) (publish X+1) -> 6; +A(X+3) -> 8. Invariant.
  // DMA cover for tile X+3: issued Phase(X), published at VMW@PH_A(X+2)
  // -> ~2 full K-tiles of landing slack.
  // LDS write hazards: STG B/A(X+3) over buf (X-1)&3 whose last reads (H2(X-1))
  // lgkm-drained at PH_B(X-1) entry, barrier-separated from these stages.
  for (int jj = 0; jj < 15; ++jj) {
    const int X0 = 4 * jj;
    TILE_FULL(0, 1, 3, 0, 1, X0 + 3)
    TILE_FULL(1, 2, 0, 1, 0, X0 + 4)
    TILE_FULL(2, 3, 1, 0, 1, X0 + 5)
    TILE_FULL(3, 0, 2, 1, 0, X0 + 6)
  }
  // X=60 (buf0,p0): stages tile 63 -> buf3; VMW(6) publishes 61.
  TILE_FULL(0, 1, 3, 0, 1, 63)
  // X=61 (buf1,p1): VMW(4) publishes 62. (The STG args here rewrite tile 0
  // into buf0 — dead data no one reads again; harmless, keeps macro shape.
  // These extra gloads retire at the VMW(0) below.)
  PH_A(1, 1, 0, 0, VMW(4))
  PH_B(2, 1, 0, 0, 0)
  // X=62 (buf2,p0): in-flight = tile 63 (4); VMW(0) publishes 63.
  LGKM0(); RD_H2(2) MMQ(0, 0) VMW(0); RAW_BAR();
  LGKM0(); RD_H1(3, 1) MMQ(4, 0) RAW_BAR();
  // X=63 (buf3,p1): final.
  LGKM0(); RD_H2(3) MMQ(0, 1)
  LGKM0(); MMQ(4, 1)

  #undef LD_A
  #undef LD_B
  #undef RD_H1
  #undef RD_H2
  #undef STG
  #undef MMQ
  #undef PH_A
  #undef PH_B
  #undef TILE_FULL

  // epilogue: C/D layout col = lane&15, row = (lane>>4)*4 + j.
  // out = acc*rsw[row] + corr[row] + bias[col].
  float bv[4];
  #pragma unroll
  for (int n = 0; n < 4; ++n) bv[n] = bias[bcol + wc * 64 + n * 16 + fr];
  #pragma unroll
  for (int m = 0; m < 8; ++m) {
    #pragma unroll
    for (int j = 0; j < 4; ++j) {
      const int row = brow + wr * 128 + m * 16 + fq * 4 + j;
      const float rs_ = rsw[row], co_ = corr[row];
      #pragma unroll
      for (int n = 0; n < 4; ++n) {
        const int col = bcol + wc * 64 + n * 16 + fr;
        out[(size_t)row * N_DIM + col] = (float)acc[m][n][j] * rs_ + co_ + bv[n];
      }
    }
  }
}

// ---- fallback (ws too small): fused dequant bf16 128^2 tile, correct but slower ----
__global__ __launch_bounds__(256) void gemm_fallback_kernel(
    const float* __restrict__ x, const int* __restrict__ qw,
    const float* __restrict__ scale, const float* __restrict__ zp,
    const float* __restrict__ bias, float* __restrict__ out) {
  __shared__ unsigned short lds_a[128 * 32];
  __shared__ unsigned short lds_b[128 * 32];
  const int t = threadIdx.x;
  const int lane = t & 63;
  const int wid = t >> 6;
  const int wr = wid >> 1, wc = wid & 1;
  const int fr = lane & 15, fq = lane >> 4;
  const int nwg = gridDim.x;
  const int cpx = nwg >> 3;
  const int bid = blockIdx.x;
  const int swz = (bid & 7) * cpx + (bid >> 3);
  const int bx = swz & 31, by = swz >> 5;
  const int brow = by * 128, bcol = bx * 128;
  const int r0 = t >> 2, c8 = (t & 3) * 8;
  f32x4 acc[4][4] = {};
  const float ss = scale[0], zs = zp[0];
  for (int kk = 0; kk < K_DIM; kk += 32) {
    ushort8 ua[2], ub[2];
    #pragma unroll
    for (int i = 0; i < 2; ++i) {
      const float* gp = x + (size_t)(brow + i * 64 + r0) * K_DIM + kk + c8;
      float4 v0 = *(const float4*)gp;
      float4 v1 = *(const float4*)(gp + 4);
      ua[i][0] = f2bf(v0.x); ua[i][1] = f2bf(v0.y); ua[i][2] = f2bf(v0.z); ua[i][3] = f2bf(v0.w);
      ua[i][4] = f2bf(v1.x); ua[i][5] = f2bf(v1.y); ua[i][6] = f2bf(v1.z); ua[i][7] = f2bf(v1.w);
      const int* qp = qw + (size_t)(bcol + i * 64 + r0) * K_DIM + kk + c8;
      int4 q0 = *(const int4*)qp;
      int4 q1 = *(const int4*)(qp + 4);
      ub[i][0] = f2bf(ss * ((float)q0.x - zs)); ub[i][1] = f2bf(ss * ((float)q0.y - zs));
      ub[i][2] = f2bf(ss * ((float)q0.z - zs)); ub[i][3] = f2bf(ss * ((float)q0.w - zs));
      ub[i][4] = f2bf(ss * ((float)q1.x - zs)); ub[i][5] = f2bf(ss * ((float)q1.y - zs));
      ub[i][6] = f2bf(ss * ((float)q1.z - zs)); ub[i][7] = f2bf(ss * ((float)q1.w - zs));
    }
    __syncthreads();
    #pragma unroll
    for (int i = 0; i < 2; ++i) {
      *(ushort8*)(lds_a + ((size_t)i * 256 + t) * 8) = ua[i];
      *(ushort8*)(lds_b + ((size_t)i * 256 + t) * 8) = ub[i];
    }
    __syncthreads();
    bf16x8 af[4], bfr[4];
    #pragma unroll
    for (int m = 0; m < 4; ++m)
      af[m] = *(const bf16x8*)(lds_a + (wr * 64 + m * 16 + fr) * 32 + fq * 8);
    #pragma unroll
    for (int n = 0; n < 4; ++n)
      bfr[n] = *(const bf16x8*)(lds_b + (wc * 64 + n * 16 + fr) * 32 + fq * 8);
    #pragma unroll
    for (int m = 0; m < 4; ++m)
      #pragma unroll
      for (int n = 0; n < 4; ++n)
        acc[m][n] = __builtin_amdgcn_mfma_f32_16x16x32_bf16(af[m], bfr[n], acc[m][n], 0, 0, 0);
  }
  #pragma unroll
  for (int n = 0; n < 4; ++n) {
    const int col = bcol + wc * 64 + n * 16 + fr;
    const float bvv = bias[col];
    #pragma unroll
    for (int m = 0; m < 4; ++m) {
      const int rowb = brow + wr * 64 + m * 16 + fq * 4;
      #pragma unroll
      for (int j = 0; j < 4; ++j)
        out[(size_t)(rowb + j) * N_DIM + col] = acc[m][n][j] + bvv;
    }
  }
}

extern "C" void kernel_launch(void* const* d_in, const int* in_sizes, int n_in,
                              void* d_out, int out_size, void* d_ws, size_t ws_size,
                              hipStream_t stream) {
  const float* x = (const float*)d_in[0];
  const int* qw = (const int*)d_in[1];
  const float* scale = (const float*)d_in[2];
  const float* zp = (const float*)d_in[3];
  const float* bias = (const float*)d_in[4];
  float* out = (float*)d_out;

  const size_t xq_bytes = (size_t)M_DIM * K_DIM;          // 32 MB
  const size_t wq_bytes = (size_t)N_DIM * K_DIM;          // 16 MB
  const size_t rsw_bytes = (size_t)M_DIM * 4;             // 32 KB
  const size_t need = xq_bytes + wq_bytes + 2 * rsw_bytes;

  if (ws_size >= need) {
    char* xq = (char*)d_ws;
    char* wq = (char*)d_ws + xq_bytes;
    float* rsw = (float*)((char*)d_ws + xq_bytes + wq_bytes);
    float* corr = rsw + M_DIM;
    prepack_kernel<<<M_DIM + WBLOCKS, 256, 0, stream>>>(x, qw, scale, zp, xq, wq, rsw, corr);
    const int grid = (M_DIM / 256) * (N_DIM / 256);  // 512, divisible by 8
    gemm256_i8_kernel<<<grid, 512, 0, stream>>>(xq, wq, rsw, corr, bias, out);
  } else {
    const int grid = (M_DIM / 128) * (N_DIM / 128);  // 2048
    gemm_fallback_kernel<<<grid, 256, 0, stream>>>(x, qw, scale, zp, bias, out);
  }
}